// Round 5
// baseline (1484.753 us; speedup 1.0000x reference)
//
#include <hip/hip_runtime.h>

typedef __attribute__((ext_vector_type(8))) short bf16x8;
typedef __attribute__((ext_vector_type(4))) float f32x4;
typedef unsigned short u16;
typedef unsigned int u32;

#define NN 1024
#define ETOT 523776
#define EPSV 1e-5f
#define NTILES 8256

// LDS layout (bytes)
#define L_PSUM 0      /* 64*8*4 = 2048 */
#define L_PSQ  2048   /* 2048 */
#define L_SSC  4096   /* 256 */
#define L_SSM  4352   /* 256 */
#define L_B1   4608   /* 2048 */
#define L_G    6656   /* 1024 */
#define L_BB   7680   /* 1024 */
#define L_W3   8704   /* 1024 */
#define L_TILE 9728   /* 64 KiB: A1 [64][256]bf16 (swz, 32K) aliased under h1 [64][512]bf16 (swz, 64K) */
#define L_TOTAL 75264 /* 2 blocks/CU */

__device__ __forceinline__ u16 f2bf(float f) {
  union { float f; u32 u; } v; v.f = f;
  u32 r = v.u + 0x7FFFu + ((v.u >> 16) & 1u);   // RNE, finite inputs only
  return (u16)(r >> 16);
}
__device__ __forceinline__ u32 pk2(float a, float b) {
  return (u32)f2bf(a) | ((u32)f2bf(b) << 16);
}

// ---- prep: W1^T [512][256] bf16 and (gamma-scaled) W2^T [256][512] bf16 ----
__global__ void prep_wt(const float* __restrict__ W1, const float* __restrict__ W2,
                        const float* __restrict__ gammav,
                        u16* __restrict__ W1t, u16* __restrict__ W2gt) {
  int idx = blockIdx.x * 256 + threadIdx.x;      // [0, 131072)
  { int n = idx >> 8, k = idx & 255; W1t[idx] = f2bf(W1[k*512 + n]); }
  { int o = idx >> 9, c = idx & 511; W2gt[idx] = f2bf(gammav[c] * W2[c*256 + o]); }
}

// ---- prep: G[o] = sum_c gamma[c]*W2[c,o]; BB[o] = b2[o] + sum_c beta[c]*W2[c,o] ----
__global__ void prep_vec(const float* __restrict__ W2, const float* __restrict__ gammav,
                         const float* __restrict__ betav, const float* __restrict__ b2v,
                         float* __restrict__ Gv, float* __restrict__ BBv) {
  int o = blockIdx.x, t = threadIdx.x;           // 256 blocks x 64 threads
  float g = 0.f, bb = 0.f;
  for (int c = t; c < 512; c += 64) {
    float w = W2[c*256 + o];
    g  += gammav[c] * w;
    bb += betav[c]  * w;
  }
  #pragma unroll
  for (int off = 1; off < 64; off <<= 1) {
    g  += __shfl_xor(g,  off, 64);
    bb += __shfl_xor(bb, off, 64);
  }
  if (t == 0) { Gv[o] = g; BBv[o] = bb + b2v[o]; }
}

// ---- main persistent fused kernel ----
__launch_bounds__(512, 4)
__global__ void edge_main(const float* __restrict__ emb,
                          const float* __restrict__ b1v,
                          const float* __restrict__ b3v,
                          const float* __restrict__ w3v,
                          const float* __restrict__ Gv,
                          const float* __restrict__ BBv,
                          const u16* __restrict__ W1t,
                          const u16* __restrict__ W2gt,
                          float* __restrict__ out) {
  extern __shared__ char smem[];
  float* psum = (float*)(smem + L_PSUM);
  float* psq  = (float*)(smem + L_PSQ);
  float* ssc  = (float*)(smem + L_SSC);
  float* ssm  = (float*)(smem + L_SSM);
  float* sb1  = (float*)(smem + L_B1);
  float* sG   = (float*)(smem + L_G);
  float* sBB  = (float*)(smem + L_BB);
  float* sw3  = (float*)(smem + L_W3);
  char*  tile = smem + L_TILE;

  const int tid  = threadIdx.x;
  const int wave = tid >> 6;
  const int lane = tid & 63;
  const int llo  = lane & 15;
  const int lhi  = lane >> 4;
  const int sw   = (llo & 7) << 4;
  const int trow = tid >> 3, cg = tid & 7;
  const int sa   = trow >> 3, sb = trow & 7;
  const int srs  = (trow & 7) << 4;

  // prologue: constants
  sb1[tid] = b1v[tid];
  if (tid < 256) { sG[tid] = Gv[tid]; sBB[tid] = BBv[tid]; sw3[tid] = w3v[tid]; }
  const float b3s = b3v[0];

  // chunked tile range: blocks 0..63 get 17 tiles, 64..511 get 16  (64*17+448*16 = 8256)
  const int bid = blockIdx.x;
  const int t0 = bid*16 + (bid < 64 ? bid : 64);
  const int t1 = t0 + 16 + (bid < 64 ? 1 : 0);

  // (bi,bj) for t0
  int bi = (int)((257.0f - sqrtf(66049.0f - 8.0f*(float)t0)) * 0.5f);
  bi = bi < 0 ? 0 : (bi > 127 ? 127 : bi);
  while (bi*128 - bi*(bi-1)/2 > t0) --bi;
  while ((bi+1)*128 - (bi+1)*bi/2 <= t0) ++bi;
  int bj = bi + (t0 - (bi*128 - bi*(bi-1)/2));

  float4 eA0, eA1, eA2, eA3, eB0, eB1, eB2, eB3;

  // stage first tile
  {
    const float4* pei = (const float4*)(emb + (bi*8 + sa)*128 + cg*16);
    const float4* pej = (const float4*)(emb + (bj*8 + sb)*128 + cg*16);
    eA0 = pei[0]; eA1 = pei[1]; eA2 = pei[2]; eA3 = pei[3];
    eB0 = pej[0]; eB1 = pej[1]; eB2 = pej[2]; eB3 = pej[3];
    char* rowp = tile + trow*512;
    uint4 v;
    v.x = pk2(eA0.x-eB0.x, eA0.y-eB0.y); v.y = pk2(eA0.z-eB0.z, eA0.w-eB0.w);
    v.z = pk2(eA1.x-eB1.x, eA1.y-eB1.y); v.w = pk2(eA1.z-eB1.z, eA1.w-eB1.w);
    *(uint4*)(rowp + ((cg*32) ^ srs)) = v;
    v.x = pk2(eA2.x-eB2.x, eA2.y-eB2.y); v.y = pk2(eA2.z-eB2.z, eA2.w-eB2.w);
    v.z = pk2(eA3.x-eB3.x, eA3.y-eB3.y); v.w = pk2(eA3.z-eB3.z, eA3.w-eB3.w);
    *(uint4*)(rowp + ((cg*32 + 16) ^ srs)) = v;
    v.x = pk2(eA0.x*eB0.x, eA0.y*eB0.y); v.y = pk2(eA0.z*eB0.z, eA0.w*eB0.w);
    v.z = pk2(eA1.x*eB1.x, eA1.y*eB1.y); v.w = pk2(eA1.z*eB1.z, eA1.w*eB1.w);
    *(uint4*)(rowp + ((256 + cg*32) ^ srs)) = v;
    v.x = pk2(eA2.x*eB2.x, eA2.y*eB2.y); v.y = pk2(eA2.z*eB2.z, eA2.w*eB2.w);
    v.z = pk2(eA3.x*eB3.x, eA3.y*eB3.y); v.w = pk2(eA3.z*eB3.z, eA3.w*eB3.w);
    *(uint4*)(rowp + ((256 + cg*32 + 16) ^ srs)) = v;
  }
  __syncthreads();                               // B0: stage + prologue visible

  int pi0 = 0, pj0 = 0;                          // previous tile origin (for logits flush)

  for (int tt = t0; tt < t1; ++tt) {
    const int i0 = bi*8, j0 = bj*8;
    const bool have_next = (tt + 1 < t1);
    int bi2 = bi, bj2 = bj + 1;
    if (bj2 == 128) { ++bi2; bj2 = bi2; }

    // ---- phase A: flush previous logits (wave0) while others GEMM1 ----
    if (tt > t0 && tid < 64) {
      float s = 0.f;
      #pragma unroll
      for (int w = 0; w < 8; ++w) s += psum[tid*8 + w];
      float logit = s + b3s;
      int a = tid >> 3, b = tid & 7;
      int i = pi0 + a, j = pj0 + b;
      if (i < j) {
        int e = i*(2*NN - i - 1)/2 + (j - i - 1);
        out[e] = logit;
        out[ETOT + 2*e]     = (float)i;
        out[ETOT + 2*e + 1] = (float)j;
      }
    }

    // ---- GEMM1: A1[64x256] @ W1[256x512]; wave owns 64-col stripe ----
    f32x4 acc1[4][4];
    #pragma unroll
    for (int m = 0; m < 4; ++m)
      #pragma unroll
      for (int n = 0; n < 4; ++n)
        acc1[m][n] = (f32x4){0.f, 0.f, 0.f, 0.f};

    const u16* w1p = W1t + (wave*64 + llo)*256 + lhi*8;
    #pragma unroll
    for (int kb = 0; kb < 8; ++kb) {
      bf16x8 af[4], bfr[4];
      #pragma unroll
      for (int m = 0; m < 4; ++m)
        af[m] = *(const bf16x8*)(tile + (m*16 + llo)*512 + ((kb*64 + lhi*16) ^ sw));
      #pragma unroll
      for (int n = 0; n < 4; ++n)
        bfr[n] = *(const bf16x8*)(w1p + n*4096 + kb*32);
      #pragma unroll
      for (int m = 0; m < 4; ++m)
        #pragma unroll
        for (int n = 0; n < 4; ++n)
          acc1[m][n] = __builtin_amdgcn_mfma_f32_16x16x32_bf16(af[m], bfr[n], acc1[m][n], 0, 0, 0);
    }

    // relu(+b1) in registers
    #pragma unroll
    for (int m = 0; m < 4; ++m)
      #pragma unroll
      for (int n = 0; n < 4; ++n) {
        int col = wave*64 + n*16 + llo;
        float bb = sb1[col];
        #pragma unroll
        for (int q = 0; q < 4; ++q)
          acc1[m][n][q] = fmaxf(acc1[m][n][q] + bb, 0.f);
      }

    __syncthreads();                             // B1: all GEMM1 A1-reads done

    // ---- phase B: write h1 (bf16, swz) + LN partial sums ----
    #pragma unroll
    for (int m = 0; m < 4; ++m) {
      #pragma unroll
      for (int q = 0; q < 4; ++q) {
        int r = m*16 + lhi*4 + q;
        int rs2 = (r & 7) << 4;
        char* rowp = tile + r*1024;
        float sum = 0.f, sq = 0.f;
        #pragma unroll
        for (int n = 0; n < 4; ++n) {
          int col = wave*64 + n*16 + llo;
          float v = acc1[m][n][q];
          *(u16*)(rowp + ((col*2) ^ rs2)) = f2bf(v);
          sum += v;
          sq  += v*v;
        }
        #pragma unroll
        for (int off = 1; off < 16; off <<= 1) {
          sum += __shfl_xor(sum, off, 64);
          sq  += __shfl_xor(sq,  off, 64);
        }
        if (llo == 0) { psum[r*8 + wave] = sum; psq[r*8 + wave] = sq; }
      }
    }
    __syncthreads();                             // B2: h1 + partials visible

    // ---- phase C: stats (wave0) ; next-tile loads ; GEMM2 ----
    if (tid < 64) {
      float s = 0.f, ss = 0.f;
      #pragma unroll
      for (int w = 0; w < 8; ++w) { s += psum[tid*8 + w]; ss += psq[tid*8 + w]; }
      float mu  = s * (1.f/512.f);
      float var = ss * (1.f/512.f) - mu*mu;
      float sc  = rsqrtf(var + EPSV);
      ssc[tid] = sc;
      ssm[tid] = mu * sc;
    }
    if (have_next) {
      const float4* pei = (const float4*)(emb + (bi2*8 + sa)*128 + cg*16);
      const float4* pej = (const float4*)(emb + (bj2*8 + sb)*128 + cg*16);
      eA0 = pei[0]; eA1 = pei[1]; eA2 = pei[2]; eA3 = pei[3];
      eB0 = pej[0]; eB1 = pej[1]; eB2 = pej[2]; eB3 = pej[3];
    }

    // GEMM2: h1[64x512] @ W2g[512x256]; wave owns 32-col stripe
    f32x4 acc2[4][2];
    #pragma unroll
    for (int m = 0; m < 4; ++m) { acc2[m][0] = (f32x4){0,0,0,0}; acc2[m][1] = (f32x4){0,0,0,0}; }

    const u16* w2p = W2gt + (wave*32 + llo)*512 + lhi*8;
    #pragma unroll 4
    for (int kb = 0; kb < 16; ++kb) {
      bf16x8 af[4], bfr[2];
      #pragma unroll
      for (int m = 0; m < 4; ++m)
        af[m] = *(const bf16x8*)(tile + (m*16 + llo)*1024 + ((kb*64 + lhi*16) ^ sw));
      #pragma unroll
      for (int n = 0; n < 2; ++n)
        bfr[n] = *(const bf16x8*)(w2p + n*8192 + kb*32);
      #pragma unroll
      for (int m = 0; m < 4; ++m)
        #pragma unroll
        for (int n = 0; n < 2; ++n)
          acc2[m][n] = __builtin_amdgcn_mfma_f32_16x16x32_bf16(af[m], bfr[n], acc2[m][n], 0, 0, 0);
    }
    __syncthreads();                             // B3: GEMM2 h1-reads done, stats visible

    // ---- phase D: stage next A1 (overlaps epi2 VALU) ; epilogue2 ----
    if (have_next) {
      char* rowp = tile + trow*512;
      uint4 v;
      v.x = pk2(eA0.x-eB0.x, eA0.y-eB0.y); v.y = pk2(eA0.z-eB0.z, eA0.w-eB0.w);
      v.z = pk2(eA1.x-eB1.x, eA1.y-eB1.y); v.w = pk2(eA1.z-eB1.z, eA1.w-eB1.w);
      *(uint4*)(rowp + ((cg*32) ^ srs)) = v;
      v.x = pk2(eA2.x-eB2.x, eA2.y-eB2.y); v.y = pk2(eA2.z-eB2.z, eA2.w-eB2.w);
      v.z = pk2(eA3.x-eB3.x, eA3.y-eB3.y); v.w = pk2(eA3.z-eB3.z, eA3.w-eB3.w);
      *(uint4*)(rowp + ((cg*32 + 16) ^ srs)) = v;
      v.x = pk2(eA0.x*eB0.x, eA0.y*eB0.y); v.y = pk2(eA0.z*eB0.z, eA0.w*eB0.w);
      v.z = pk2(eA1.x*eB1.x, eA1.y*eB1.y); v.w = pk2(eA1.z*eB1.z, eA1.w*eB1.w);
      *(uint4*)(rowp + ((256 + cg*32) ^ srs)) = v;
      v.x = pk2(eA2.x*eB2.x, eA2.y*eB2.y); v.y = pk2(eA2.z*eB2.z, eA2.w*eB2.w);
      v.z = pk2(eA3.x*eB3.x, eA3.y*eB3.y); v.w = pk2(eA3.z*eB3.z, eA3.w*eB3.w);
      *(uint4*)(rowp + ((256 + cg*32 + 16) ^ srs)) = v;
    }

    // epi2: LN-affine + relu + W3 dot, per-row reduce
    #pragma unroll
    for (int m = 0; m < 4; ++m) {
      float cgv[2], cbv[2], cwv[2];
      #pragma unroll
      for (int n = 0; n < 2; ++n) {
        int col = wave*32 + n*16 + llo;
        cgv[n] = sG[col]; cbv[n] = sBB[col]; cwv[n] = sw3[col];
      }
      #pragma unroll
      for (int q = 0; q < 4; ++q) {
        int r = m*16 + lhi*4 + q;
        float sc = ssc[r], sm = ssm[r];
        float s = 0.f;
        #pragma unroll
        for (int n = 0; n < 2; ++n) {
          float v = sc*acc2[m][n][q] - sm*cgv[n] + cbv[n];
          v = fmaxf(v, 0.f);
          s += v * cwv[n];
        }
        #pragma unroll
        for (int off = 1; off < 16; off <<= 1) s += __shfl_xor(s, off, 64);
        if (llo == 0) psum[r*8 + wave] = s;
      }
    }
    __syncthreads();                             // B4: psum + next A1 ready

    pi0 = i0; pj0 = j0;
    ++bj; if (bj == 128) { ++bi; bj = bi; }
  }

  // final flush
  if (tid < 64) {
    float s = 0.f;
    #pragma unroll
    for (int w = 0; w < 8; ++w) s += psum[tid*8 + w];
    float logit = s + b3s;
    int a = tid >> 3, b = tid & 7;
    int i = pi0 + a, j = pj0 + b;
    if (i < j) {
      int e = i*(2*NN - i - 1)/2 + (j - i - 1);
      out[e] = logit;
      out[ETOT + 2*e]     = (float)i;
      out[ETOT + 2*e + 1] = (float)j;
    }
  }
}

extern "C" void kernel_launch(void* const* d_in, const int* in_sizes, int n_in,
                              void* d_out, int out_size, void* d_ws, size_t ws_size,
                              hipStream_t stream) {
  const float* emb   = (const float*)d_in[0];
  const float* W1    = (const float*)d_in[1];
  const float* b1    = (const float*)d_in[2];
  const float* gamma = (const float*)d_in[3];
  const float* beta  = (const float*)d_in[4];
  const float* W2    = (const float*)d_in[5];
  const float* b2    = (const float*)d_in[6];
  const float* W3    = (const float*)d_in[7];
  const float* b3    = (const float*)d_in[8];

  char* ws   = (char*)d_ws;
  u16*  W1t  = (u16*)ws;                         // 256 KiB
  u16*  W2gt = (u16*)(ws + 512*256*2);           // 256 KiB
  float* Gv  = (float*)(ws + 512*256*2*2);       // 1 KiB
  float* BBv = (float*)(ws + 512*256*2*2 + 1024);// 1 KiB

  (void)hipFuncSetAttribute((const void*)edge_main,
                            hipFuncAttributeMaxDynamicSharedMemorySize, L_TOTAL);

  prep_wt<<<512, 256, 0, stream>>>(W1, W2, gamma, W1t, W2gt);
  prep_vec<<<256, 64, 0, stream>>>(W2, gamma, beta, b2, Gv, BBv);
  edge_main<<<512, 512, L_TOTAL, stream>>>(emb, b1, b3, W3, Gv, BBv,
                                           W1t, W2gt, (float*)d_out);
}

// Round 6
// 1410.512 us; speedup vs baseline: 1.0526x; 1.0526x over previous
//
#include <hip/hip_runtime.h>

typedef __attribute__((ext_vector_type(8))) short bf16x8;
typedef __attribute__((ext_vector_type(4))) float f32x4;
typedef unsigned short u16;
typedef unsigned int u32;

#define NN 1024
#define ETOT 523776
#define EPSV 1e-5f
#define NTILES 8256

// LDS layout (bytes)
#define L_PSUM 0      /* 64*8*4 = 2048 */
#define L_PSQ  2048   /* 2048 */
#define L_SSC  4096   /* 256 */
#define L_SSM  4352   /* 256 */
#define L_B1   4608   /* 2048 */
#define L_G    6656   /* 1024 */
#define L_BB   7680   /* 1024 */
#define L_W3   8704   /* 1024 */
#define L_TILE 9728   /* 64 KiB: A1 [64][256]bf16 (swz, 32K) aliased under h1 [64][512]bf16 (swz, 64K) */
#define L_TOTAL 75264 /* 2 blocks/CU */

__device__ __forceinline__ u16 f2bf(float f) {
  union { float f; u32 u; } v; v.f = f;
  u32 r = v.u + 0x7FFFu + ((v.u >> 16) & 1u);   // RNE, finite inputs only
  return (u16)(r >> 16);
}
__device__ __forceinline__ u32 pk2(float a, float b) {
  return (u32)f2bf(a) | ((u32)f2bf(b) << 16);
}

// ---- prep: W1^T [512][256] bf16 and (gamma-scaled) W2^T [256][512] bf16 ----
__global__ void prep_wt(const float* __restrict__ W1, const float* __restrict__ W2,
                        const float* __restrict__ gammav,
                        u16* __restrict__ W1t, u16* __restrict__ W2gt) {
  int idx = blockIdx.x * 256 + threadIdx.x;      // [0, 131072)
  { int n = idx >> 8, k = idx & 255; W1t[idx] = f2bf(W1[k*512 + n]); }
  { int o = idx >> 9, c = idx & 511; W2gt[idx] = f2bf(gammav[c] * W2[c*256 + o]); }
}

// ---- prep: G[o] = sum_c gamma[c]*W2[c,o]; BB[o] = b2[o] + sum_c beta[c]*W2[c,o] ----
__global__ void prep_vec(const float* __restrict__ W2, const float* __restrict__ gammav,
                         const float* __restrict__ betav, const float* __restrict__ b2v,
                         float* __restrict__ Gv, float* __restrict__ BBv) {
  int o = blockIdx.x, t = threadIdx.x;           // 256 blocks x 64 threads
  float g = 0.f, bb = 0.f;
  for (int c = t; c < 512; c += 64) {
    float w = W2[c*256 + o];
    g  += gammav[c] * w;
    bb += betav[c]  * w;
  }
  #pragma unroll
  for (int off = 1; off < 64; off <<= 1) {
    g  += __shfl_xor(g,  off, 64);
    bb += __shfl_xor(bb, off, 64);
  }
  if (t == 0) { Gv[o] = g; BBv[o] = bb + b2v[o]; }
}

// ---- main persistent fused kernel ----
__launch_bounds__(512, 2)
__global__ void edge_main(const float* __restrict__ emb,
                          const float* __restrict__ b1v,
                          const float* __restrict__ b3v,
                          const float* __restrict__ w3v,
                          const float* __restrict__ Gv,
                          const float* __restrict__ BBv,
                          const u16* __restrict__ W1t,
                          const u16* __restrict__ W2gt,
                          float* __restrict__ out) {
  extern __shared__ char smem[];
  float* psum = (float*)(smem + L_PSUM);
  float* psq  = (float*)(smem + L_PSQ);
  float* ssc  = (float*)(smem + L_SSC);
  float* ssm  = (float*)(smem + L_SSM);
  float* sb1  = (float*)(smem + L_B1);
  float* sG   = (float*)(smem + L_G);
  float* sBB  = (float*)(smem + L_BB);
  float* sw3  = (float*)(smem + L_W3);
  char*  tile = smem + L_TILE;

  const int tid  = threadIdx.x;
  const int wave = tid >> 6;
  const int lane = tid & 63;
  const int llo  = lane & 15;
  const int lhi  = lane >> 4;
  const int sw   = (llo & 7) << 4;
  const int trow = tid >> 3, cg = tid & 7;
  const int sa   = trow >> 3, sb = trow & 7;
  const int srs  = (trow & 7) << 4;

  // prologue: constants
  sb1[tid] = b1v[tid];
  if (tid < 256) { sG[tid] = Gv[tid]; sBB[tid] = BBv[tid]; sw3[tid] = w3v[tid]; }
  const float b3s = b3v[0];

  // chunked tile range: blocks 0..63 get 17 tiles, 64..511 get 16  (64*17+448*16 = 8256)
  const int bid = blockIdx.x;
  const int t0 = bid*16 + (bid < 64 ? bid : 64);
  const int t1 = t0 + 16 + (bid < 64 ? 1 : 0);

  // (bi,bj) for t0
  int bi = (int)((257.0f - sqrtf(66049.0f - 8.0f*(float)t0)) * 0.5f);
  bi = bi < 0 ? 0 : (bi > 127 ? 127 : bi);
  while (bi*128 - bi*(bi-1)/2 > t0) --bi;
  while ((bi+1)*128 - (bi+1)*bi/2 <= t0) ++bi;
  int bj = bi + (t0 - (bi*128 - bi*(bi-1)/2));

  float4 eA0, eA1, eA2, eA3, eB0, eB1, eB2, eB3;

  // stage first tile
  {
    const float4* pei = (const float4*)(emb + (bi*8 + sa)*128 + cg*16);
    const float4* pej = (const float4*)(emb + (bj*8 + sb)*128 + cg*16);
    eA0 = pei[0]; eA1 = pei[1]; eA2 = pei[2]; eA3 = pei[3];
    eB0 = pej[0]; eB1 = pej[1]; eB2 = pej[2]; eB3 = pej[3];
    char* rowp = tile + trow*512;
    uint4 v;
    v.x = pk2(eA0.x-eB0.x, eA0.y-eB0.y); v.y = pk2(eA0.z-eB0.z, eA0.w-eB0.w);
    v.z = pk2(eA1.x-eB1.x, eA1.y-eB1.y); v.w = pk2(eA1.z-eB1.z, eA1.w-eB1.w);
    *(uint4*)(rowp + ((cg*32) ^ srs)) = v;
    v.x = pk2(eA2.x-eB2.x, eA2.y-eB2.y); v.y = pk2(eA2.z-eB2.z, eA2.w-eB2.w);
    v.z = pk2(eA3.x-eB3.x, eA3.y-eB3.y); v.w = pk2(eA3.z-eB3.z, eA3.w-eB3.w);
    *(uint4*)(rowp + ((cg*32 + 16) ^ srs)) = v;
    v.x = pk2(eA0.x*eB0.x, eA0.y*eB0.y); v.y = pk2(eA0.z*eB0.z, eA0.w*eB0.w);
    v.z = pk2(eA1.x*eB1.x, eA1.y*eB1.y); v.w = pk2(eA1.z*eB1.z, eA1.w*eB1.w);
    *(uint4*)(rowp + ((256 + cg*32) ^ srs)) = v;
    v.x = pk2(eA2.x*eB2.x, eA2.y*eB2.y); v.y = pk2(eA2.z*eB2.z, eA2.w*eB2.w);
    v.z = pk2(eA3.x*eB3.x, eA3.y*eB3.y); v.w = pk2(eA3.z*eB3.z, eA3.w*eB3.w);
    *(uint4*)(rowp + ((256 + cg*32 + 16) ^ srs)) = v;
  }
  __syncthreads();                               // B0: stage + prologue visible

  int pi0 = 0, pj0 = 0;                          // previous tile origin (for logits flush)

  for (int tt = t0; tt < t1; ++tt) {
    const int i0 = bi*8, j0 = bj*8;
    const bool have_next = (tt + 1 < t1);
    int bi2 = bi, bj2 = bj + 1;
    if (bj2 == 128) { ++bi2; bj2 = bi2; }

    // ---- phase A: flush previous logits (wave0) while others GEMM1 ----
    if (tt > t0 && tid < 64) {
      float s = 0.f;
      #pragma unroll
      for (int w = 0; w < 8; ++w) s += psum[tid*8 + w];
      float logit = s + b3s;
      int a = tid >> 3, b = tid & 7;
      int i = pi0 + a, j = pj0 + b;
      if (i < j) {
        int e = i*(2*NN - i - 1)/2 + (j - i - 1);
        out[e] = logit;
        out[ETOT + 2*e]     = (float)i;
        out[ETOT + 2*e + 1] = (float)j;
      }
    }

    // ---- GEMM1: A1[64x256] @ W1[256x512]; wave owns 64-col stripe ----
    f32x4 acc1[4][4];
    #pragma unroll
    for (int m = 0; m < 4; ++m)
      #pragma unroll
      for (int n = 0; n < 4; ++n)
        acc1[m][n] = (f32x4){0.f, 0.f, 0.f, 0.f};

    const u16* w1p = W1t + (wave*64 + llo)*256 + lhi*8;
    #pragma unroll
    for (int kb = 0; kb < 8; ++kb) {
      bf16x8 af[4], bfr[4];
      #pragma unroll
      for (int m = 0; m < 4; ++m)
        af[m] = *(const bf16x8*)(tile + (m*16 + llo)*512 + ((kb*64 + lhi*16) ^ sw));
      #pragma unroll
      for (int n = 0; n < 4; ++n)
        bfr[n] = *(const bf16x8*)(w1p + n*4096 + kb*32);
      #pragma unroll
      for (int m = 0; m < 4; ++m)
        #pragma unroll
        for (int n = 0; n < 4; ++n)
          acc1[m][n] = __builtin_amdgcn_mfma_f32_16x16x32_bf16(af[m], bfr[n], acc1[m][n], 0, 0, 0);
    }

    // relu(+b1) in registers
    #pragma unroll
    for (int m = 0; m < 4; ++m)
      #pragma unroll
      for (int n = 0; n < 4; ++n) {
        int col = wave*64 + n*16 + llo;
        float bb = sb1[col];
        #pragma unroll
        for (int q = 0; q < 4; ++q)
          acc1[m][n][q] = fmaxf(acc1[m][n][q] + bb, 0.f);
      }

    __syncthreads();                             // B1: all GEMM1 A1-reads done

    // ---- phase B: write h1 (bf16, swz) + LN partial sums ----
    #pragma unroll
    for (int m = 0; m < 4; ++m) {
      #pragma unroll
      for (int q = 0; q < 4; ++q) {
        int r = m*16 + lhi*4 + q;
        int rs2 = (r & 7) << 4;
        char* rowp = tile + r*1024;
        float sum = 0.f, sq = 0.f;
        #pragma unroll
        for (int n = 0; n < 4; ++n) {
          int col = wave*64 + n*16 + llo;
          float v = acc1[m][n][q];
          *(u16*)(rowp + ((col*2) ^ rs2)) = f2bf(v);
          sum += v;
          sq  += v*v;
        }
        #pragma unroll
        for (int off = 1; off < 16; off <<= 1) {
          sum += __shfl_xor(sum, off, 64);
          sq  += __shfl_xor(sq,  off, 64);
        }
        if (llo == 0) { psum[r*8 + wave] = sum; psq[r*8 + wave] = sq; }
      }
    }
    __syncthreads();                             // B2: h1 + partials visible

    // ---- phase C: stats (wave0) ; next-tile loads ; GEMM2 ----
    if (tid < 64) {
      float s = 0.f, ss = 0.f;
      #pragma unroll
      for (int w = 0; w < 8; ++w) { s += psum[tid*8 + w]; ss += psq[tid*8 + w]; }
      float mu  = s * (1.f/512.f);
      float var = ss * (1.f/512.f) - mu*mu;
      float sc  = rsqrtf(var + EPSV);
      ssc[tid] = sc;
      ssm[tid] = mu * sc;
    }
    if (have_next) {
      const float4* pei = (const float4*)(emb + (bi2*8 + sa)*128 + cg*16);
      const float4* pej = (const float4*)(emb + (bj2*8 + sb)*128 + cg*16);
      eA0 = pei[0]; eA1 = pei[1]; eA2 = pei[2]; eA3 = pei[3];
      eB0 = pej[0]; eB1 = pej[1]; eB2 = pej[2]; eB3 = pej[3];
    }

    // GEMM2: h1[64x512] @ W2g[512x256]; wave owns 32-col stripe
    f32x4 acc2[4][2];
    #pragma unroll
    for (int m = 0; m < 4; ++m) { acc2[m][0] = (f32x4){0,0,0,0}; acc2[m][1] = (f32x4){0,0,0,0}; }

    const u16* w2p = W2gt + (wave*32 + llo)*512 + lhi*8;
    #pragma unroll 4
    for (int kb = 0; kb < 16; ++kb) {
      bf16x8 af[4], bfr[2];
      #pragma unroll
      for (int m = 0; m < 4; ++m)
        af[m] = *(const bf16x8*)(tile + (m*16 + llo)*1024 + ((kb*64 + lhi*16) ^ sw));
      #pragma unroll
      for (int n = 0; n < 2; ++n)
        bfr[n] = *(const bf16x8*)(w2p + n*8192 + kb*32);
      #pragma unroll
      for (int m = 0; m < 4; ++m)
        #pragma unroll
        for (int n = 0; n < 2; ++n)
          acc2[m][n] = __builtin_amdgcn_mfma_f32_16x16x32_bf16(af[m], bfr[n], acc2[m][n], 0, 0, 0);
    }
    __syncthreads();                             // B3: GEMM2 h1-reads done, stats visible

    // ---- phase D: stage next A1 (overlaps epi2 VALU) ; epilogue2 ----
    if (have_next) {
      char* rowp = tile + trow*512;
      uint4 v;
      v.x = pk2(eA0.x-eB0.x, eA0.y-eB0.y); v.y = pk2(eA0.z-eB0.z, eA0.w-eB0.w);
      v.z = pk2(eA1.x-eB1.x, eA1.y-eB1.y); v.w = pk2(eA1.z-eB1.z, eA1.w-eB1.w);
      *(uint4*)(rowp + ((cg*32) ^ srs)) = v;
      v.x = pk2(eA2.x-eB2.x, eA2.y-eB2.y); v.y = pk2(eA2.z-eB2.z, eA2.w-eB2.w);
      v.z = pk2(eA3.x-eB3.x, eA3.y-eB3.y); v.w = pk2(eA3.z-eB3.z, eA3.w-eB3.w);
      *(uint4*)(rowp + ((cg*32 + 16) ^ srs)) = v;
      v.x = pk2(eA0.x*eB0.x, eA0.y*eB0.y); v.y = pk2(eA0.z*eB0.z, eA0.w*eB0.w);
      v.z = pk2(eA1.x*eB1.x, eA1.y*eB1.y); v.w = pk2(eA1.z*eB1.z, eA1.w*eB1.w);
      *(uint4*)(rowp + ((256 + cg*32) ^ srs)) = v;
      v.x = pk2(eA2.x*eB2.x, eA2.y*eB2.y); v.y = pk2(eA2.z*eB2.z, eA2.w*eB2.w);
      v.z = pk2(eA3.x*eB3.x, eA3.y*eB3.y); v.w = pk2(eA3.z*eB3.z, eA3.w*eB3.w);
      *(uint4*)(rowp + ((256 + cg*32 + 16) ^ srs)) = v;
    }

    // epi2: LN-affine + relu + W3 dot, per-row reduce
    #pragma unroll
    for (int m = 0; m < 4; ++m) {
      float cgv[2], cbv[2], cwv[2];
      #pragma unroll
      for (int n = 0; n < 2; ++n) {
        int col = wave*32 + n*16 + llo;
        cgv[n] = sG[col]; cbv[n] = sBB[col]; cwv[n] = sw3[col];
      }
      #pragma unroll
      for (int q = 0; q < 4; ++q) {
        int r = m*16 + lhi*4 + q;
        float sc = ssc[r], sm = ssm[r];
        float s = 0.f;
        #pragma unroll
        for (int n = 0; n < 2; ++n) {
          float v = sc*acc2[m][n][q] - sm*cgv[n] + cbv[n];
          v = fmaxf(v, 0.f);
          s += v * cwv[n];
        }
        #pragma unroll
        for (int off = 1; off < 16; off <<= 1) s += __shfl_xor(s, off, 64);
        if (llo == 0) psum[r*8 + wave] = s;
      }
    }
    __syncthreads();                             // B4: psum + next A1 ready

    pi0 = i0; pj0 = j0;
    ++bj; if (bj == 128) { ++bi; bj = bi; }
  }

  // final flush
  if (tid < 64) {
    float s = 0.f;
    #pragma unroll
    for (int w = 0; w < 8; ++w) s += psum[tid*8 + w];
    float logit = s + b3s;
    int a = tid >> 3, b = tid & 7;
    int i = pi0 + a, j = pj0 + b;
    if (i < j) {
      int e = i*(2*NN - i - 1)/2 + (j - i - 1);
      out[e] = logit;
      out[ETOT + 2*e]     = (float)i;
      out[ETOT + 2*e + 1] = (float)j;
    }
  }
}

extern "C" void kernel_launch(void* const* d_in, const int* in_sizes, int n_in,
                              void* d_out, int out_size, void* d_ws, size_t ws_size,
                              hipStream_t stream) {
  const float* emb   = (const float*)d_in[0];
  const float* W1    = (const float*)d_in[1];
  const float* b1    = (const float*)d_in[2];
  const float* gamma = (const float*)d_in[3];
  const float* beta  = (const float*)d_in[4];
  const float* W2    = (const float*)d_in[5];
  const float* b2    = (const float*)d_in[6];
  const float* W3    = (const float*)d_in[7];
  const float* b3    = (const float*)d_in[8];

  char* ws   = (char*)d_ws;
  u16*  W1t  = (u16*)ws;                         // 256 KiB
  u16*  W2gt = (u16*)(ws + 512*256*2);           // 256 KiB
  float* Gv  = (float*)(ws + 512*256*2*2);       // 1 KiB
  float* BBv = (float*)(ws + 512*256*2*2 + 1024);// 1 KiB

  (void)hipFuncSetAttribute((const void*)edge_main,
                            hipFuncAttributeMaxDynamicSharedMemorySize, L_TOTAL);

  prep_wt<<<512, 256, 0, stream>>>(W1, W2, gamma, W1t, W2gt);
  prep_vec<<<256, 64, 0, stream>>>(W2, gamma, beta, b2, Gv, BBv);
  edge_main<<<512, 512, L_TOTAL, stream>>>(emb, b1, b3, W3, Gv, BBv,
                                           W1t, W2gt, (float*)d_out);
}

// Round 7
// 618.999 us; speedup vs baseline: 2.3986x; 2.2787x over previous
//
#include <hip/hip_runtime.h>

typedef __attribute__((ext_vector_type(8))) short bf16x8;
typedef __attribute__((ext_vector_type(4))) float f32x4;
typedef unsigned short u16;
typedef unsigned int u32;

#define NN 1024
#define ETOT 523776
#define EPSV 1e-5f

// LDS layout (bytes)
#define L_PSUM 0      /* 64*8*4 = 2048 */
#define L_PSQ  2048   /* 2048 */
#define L_SSC  4096   /* 256 */
#define L_SSM  4352   /* 256 */
#define L_B1   4608   /* 2048 */
#define L_G    6656   /* 1024 */
#define L_BB   7680   /* 1024 */
#define L_W3   8704   /* 1024 */
#define L_TILE 9728   /* 64 KiB: A1 [64][256]bf16 (swz, 32K) aliased under h1 [64][512]bf16 (swz, 64K) */
#define L_TOTAL 75264 /* 2 blocks/CU */

__device__ __forceinline__ u16 f2bf(float f) {
  union { float f; u32 u; } v; v.f = f;
  u32 r = v.u + 0x7FFFu + ((v.u >> 16) & 1u);   // RNE, finite inputs only
  return (u16)(r >> 16);
}
__device__ __forceinline__ u32 pk2(float a, float b) {
  return (u32)f2bf(a) | ((u32)f2bf(b) << 16);
}

// ---- prep: W1^T [512][256] bf16 and (gamma-scaled) W2^T [256][512] bf16 ----
__global__ void prep_wt(const float* __restrict__ W1, const float* __restrict__ W2,
                        const float* __restrict__ gammav,
                        u16* __restrict__ W1t, u16* __restrict__ W2gt) {
  int idx = blockIdx.x * 256 + threadIdx.x;      // [0, 131072)
  { int n = idx >> 8, k = idx & 255; W1t[idx] = f2bf(W1[k*512 + n]); }
  { int o = idx >> 9, c = idx & 511; W2gt[idx] = f2bf(gammav[c] * W2[c*256 + o]); }
}

// ---- prep: G[o] = sum_c gamma[c]*W2[c,o]; BB[o] = b2[o] + sum_c beta[c]*W2[c,o] ----
__global__ void prep_vec(const float* __restrict__ W2, const float* __restrict__ gammav,
                         const float* __restrict__ betav, const float* __restrict__ b2v,
                         float* __restrict__ Gv, float* __restrict__ BBv) {
  int o = blockIdx.x, t = threadIdx.x;           // 256 blocks x 64 threads
  float g = 0.f, bb = 0.f;
  for (int c = t; c < 512; c += 64) {
    float w = W2[c*256 + o];
    g  += gammav[c] * w;
    bb += betav[c]  * w;
  }
  #pragma unroll
  for (int off = 1; off < 64; off <<= 1) {
    g  += __shfl_xor(g,  off, 64);
    bb += __shfl_xor(bb, off, 64);
  }
  if (t == 0) { Gv[o] = g; BBv[o] = bb + b2v[o]; }
}

// ---- main fused kernel: one block = 8x8 node tile = 64 edge rows (straight-line) ----
__launch_bounds__(512, 4)
__global__ void edge_main(const float* __restrict__ emb,
                          const float* __restrict__ b1v,
                          const float* __restrict__ b3v,
                          const float* __restrict__ w3v,
                          const float* __restrict__ Gv,
                          const float* __restrict__ BBv,
                          const u16* __restrict__ W1t,
                          const u16* __restrict__ W2gt,
                          float* __restrict__ out) {
  extern __shared__ char smem[];
  float* psum = (float*)(smem + L_PSUM);
  float* psq  = (float*)(smem + L_PSQ);
  float* ssc  = (float*)(smem + L_SSC);
  float* ssm  = (float*)(smem + L_SSM);
  float* sb1  = (float*)(smem + L_B1);
  float* sG   = (float*)(smem + L_G);
  float* sBB  = (float*)(smem + L_BB);
  float* sw3  = (float*)(smem + L_W3);
  char*  tile = smem + L_TILE;

  const int tid  = threadIdx.x;
  const int wave = tid >> 6;
  const int lane = tid & 63;
  const int llo  = lane & 15;
  const int lhi  = lane >> 4;
  const int sw   = (llo & 7) << 4;
  const int trow = tid >> 3, cg = tid & 7;
  const int sa   = trow >> 3, sb = trow & 7;
  const int srs  = (trow & 7) << 4;

  // exact upper-triangle (incl. diagonal) tile mapping: 8256 blocks
  int kblk = blockIdx.x;
  int bi = (int)((257.0f - sqrtf(66049.0f - 8.0f*(float)kblk)) * 0.5f);
  bi = bi < 0 ? 0 : (bi > 127 ? 127 : bi);
  while (bi*128 - bi*(bi-1)/2 > kblk) --bi;
  while ((bi+1)*128 - (bi+1)*bi/2 <= kblk) ++bi;
  const int bj = bi + (kblk - (bi*128 - bi*(bi-1)/2));
  const int i0 = bi*8, j0 = bj*8;

  // ---- stage A1 = [e_i - e_j | e_i * e_j] bf16, XOR-swizzled [64][256] (512B rows) ----
  {
    const float4* pei = (const float4*)(emb + (i0 + sa)*128 + cg*16);
    const float4* pej = (const float4*)(emb + (j0 + sb)*128 + cg*16);
    float4 eA0 = pei[0], eA1 = pei[1], eA2 = pei[2], eA3 = pei[3];
    float4 eB0 = pej[0], eB1 = pej[1], eB2 = pej[2], eB3 = pej[3];
    char* rowp = tile + trow*512;
    uint4 v;
    v.x = pk2(eA0.x-eB0.x, eA0.y-eB0.y); v.y = pk2(eA0.z-eB0.z, eA0.w-eB0.w);
    v.z = pk2(eA1.x-eB1.x, eA1.y-eB1.y); v.w = pk2(eA1.z-eB1.z, eA1.w-eB1.w);
    *(uint4*)(rowp + ((cg*32) ^ srs)) = v;
    v.x = pk2(eA2.x-eB2.x, eA2.y-eB2.y); v.y = pk2(eA2.z-eB2.z, eA2.w-eB2.w);
    v.z = pk2(eA3.x-eB3.x, eA3.y-eB3.y); v.w = pk2(eA3.z-eB3.z, eA3.w-eB3.w);
    *(uint4*)(rowp + ((cg*32 + 16) ^ srs)) = v;
    v.x = pk2(eA0.x*eB0.x, eA0.y*eB0.y); v.y = pk2(eA0.z*eB0.z, eA0.w*eB0.w);
    v.z = pk2(eA1.x*eB1.x, eA1.y*eB1.y); v.w = pk2(eA1.z*eB1.z, eA1.w*eB1.w);
    *(uint4*)(rowp + ((256 + cg*32) ^ srs)) = v;
    v.x = pk2(eA2.x*eB2.x, eA2.y*eB2.y); v.y = pk2(eA2.z*eB2.z, eA2.w*eB2.w);
    v.z = pk2(eA3.x*eB3.x, eA3.y*eB3.y); v.w = pk2(eA3.z*eB3.z, eA3.w*eB3.w);
    *(uint4*)(rowp + ((256 + cg*32 + 16) ^ srs)) = v;
  }
  sb1[tid] = b1v[tid];
  if (tid < 256) { sG[tid] = Gv[tid]; sBB[tid] = BBv[tid]; sw3[tid] = w3v[tid]; }
  __syncthreads();                               // B0: stage + consts visible

  // ---- GEMM1: A1[64x256] @ W1[256x512]; wave owns 64-col stripe ----
  f32x4 acc1[4][4];
  #pragma unroll
  for (int m = 0; m < 4; ++m)
    #pragma unroll
    for (int n = 0; n < 4; ++n)
      acc1[m][n] = (f32x4){0.f, 0.f, 0.f, 0.f};

  const u16* w1p = W1t + (wave*64 + llo)*256 + lhi*8;
  #pragma unroll
  for (int kb = 0; kb < 8; ++kb) {
    bf16x8 af[4], bfr[4];
    #pragma unroll
    for (int m = 0; m < 4; ++m)
      af[m] = *(const bf16x8*)(tile + (m*16 + llo)*512 + ((kb*64 + lhi*16) ^ sw));
    #pragma unroll
    for (int n = 0; n < 4; ++n)
      bfr[n] = *(const bf16x8*)(w1p + n*4096 + kb*32);
    #pragma unroll
    for (int m = 0; m < 4; ++m)
      #pragma unroll
      for (int n = 0; n < 4; ++n)
        acc1[m][n] = __builtin_amdgcn_mfma_f32_16x16x32_bf16(af[m], bfr[n], acc1[m][n], 0, 0, 0);
  }

  // relu(+b1) in registers
  #pragma unroll
  for (int m = 0; m < 4; ++m)
    #pragma unroll
    for (int n = 0; n < 4; ++n) {
      int col = wave*64 + n*16 + llo;
      float bb = sb1[col];
      #pragma unroll
      for (int q = 0; q < 4; ++q)
        acc1[m][n][q] = fmaxf(acc1[m][n][q] + bb, 0.f);
    }
  __syncthreads();                               // B1: all GEMM1 A1-reads done

  // ---- write h1 (unnormalized bf16, swz) + LN partial sums ----
  #pragma unroll
  for (int m = 0; m < 4; ++m) {
    #pragma unroll
    for (int q = 0; q < 4; ++q) {
      int r = m*16 + lhi*4 + q;
      int rs2 = (r & 7) << 4;
      char* rowp = tile + r*1024;
      float sum = 0.f, sq = 0.f;
      #pragma unroll
      for (int n = 0; n < 4; ++n) {
        int col = wave*64 + n*16 + llo;
        float v = acc1[m][n][q];
        *(u16*)(rowp + ((col*2) ^ rs2)) = f2bf(v);
        sum += v;
        sq  += v*v;
      }
      #pragma unroll
      for (int off = 1; off < 16; off <<= 1) {
        sum += __shfl_xor(sum, off, 64);
        sq  += __shfl_xor(sq,  off, 64);
      }
      if (llo == 0) { psum[r*8 + wave] = sum; psq[r*8 + wave] = sq; }
    }
  }
  __syncthreads();                               // B2: h1 + partials visible

  // ---- stats (wave0) overlapped with GEMM2 (all waves) ----
  if (tid < 64) {
    float s = 0.f, ss = 0.f;
    #pragma unroll
    for (int w = 0; w < 8; ++w) { s += psum[tid*8 + w]; ss += psq[tid*8 + w]; }
    float mu  = s * (1.f/512.f);
    float var = ss * (1.f/512.f) - mu*mu;
    float sc  = rsqrtf(var + EPSV);
    ssc[tid] = sc;
    ssm[tid] = mu * sc;
  }

  // GEMM2: h1[64x512] @ W2g[512x256]; wave owns 32-col stripe
  f32x4 acc2[4][2];
  #pragma unroll
  for (int m = 0; m < 4; ++m) { acc2[m][0] = (f32x4){0,0,0,0}; acc2[m][1] = (f32x4){0,0,0,0}; }

  const u16* w2p = W2gt + (wave*32 + llo)*512 + lhi*8;
  #pragma unroll 4
  for (int kb = 0; kb < 16; ++kb) {
    bf16x8 af[4], bfr[2];
    #pragma unroll
    for (int m = 0; m < 4; ++m)
      af[m] = *(const bf16x8*)(tile + (m*16 + llo)*1024 + ((kb*64 + lhi*16) ^ sw));
    #pragma unroll
    for (int n = 0; n < 2; ++n)
      bfr[n] = *(const bf16x8*)(w2p + n*8192 + kb*32);
    #pragma unroll
    for (int m = 0; m < 4; ++m)
      #pragma unroll
      for (int n = 0; n < 2; ++n)
        acc2[m][n] = __builtin_amdgcn_mfma_f32_16x16x32_bf16(af[m], bfr[n], acc2[m][n], 0, 0, 0);
  }
  __syncthreads();                               // B3: stats visible (GEMM2 done)

  // ---- epilogue2: LN-affine + relu + W3 dot, per-row reduce ----
  #pragma unroll
  for (int m = 0; m < 4; ++m) {
    float cgv[2], cbv[2], cwv[2];
    #pragma unroll
    for (int n = 0; n < 2; ++n) {
      int col = wave*32 + n*16 + llo;
      cgv[n] = sG[col]; cbv[n] = sBB[col]; cwv[n] = sw3[col];
    }
    #pragma unroll
    for (int q = 0; q < 4; ++q) {
      int r = m*16 + lhi*4 + q;
      float sc = ssc[r], sm = ssm[r];
      float s = 0.f;
      #pragma unroll
      for (int n = 0; n < 2; ++n) {
        float v = sc*acc2[m][n][q] - sm*cgv[n] + cbv[n];
        v = fmaxf(v, 0.f);
        s += v * cwv[n];
      }
      #pragma unroll
      for (int off = 1; off < 16; off <<= 1) s += __shfl_xor(s, off, 64);
      if (llo == 0) psum[r*8 + wave] = s;
    }
  }
  __syncthreads();                               // B4: psum ready

  // ---- flush logits + pairs ----
  if (tid < 64) {
    float s = 0.f;
    #pragma unroll
    for (int w = 0; w < 8; ++w) s += psum[tid*8 + w];
    float logit = s + b3v[0];
    int a = tid >> 3, b = tid & 7;
    int i = i0 + a, j = j0 + b;
    if (i < j) {
      int e = i*(2*NN - i - 1)/2 + (j - i - 1);
      out[e] = logit;
      out[ETOT + 2*e]     = (float)i;
      out[ETOT + 2*e + 1] = (float)j;
    }
  }
}

extern "C" void kernel_launch(void* const* d_in, const int* in_sizes, int n_in,
                              void* d_out, int out_size, void* d_ws, size_t ws_size,
                              hipStream_t stream) {
  const float* emb   = (const float*)d_in[0];
  const float* W1    = (const float*)d_in[1];
  const float* b1    = (const float*)d_in[2];
  const float* gamma = (const float*)d_in[3];
  const float* beta  = (const float*)d_in[4];
  const float* W2    = (const float*)d_in[5];
  const float* b2    = (const float*)d_in[6];
  const float* W3    = (const float*)d_in[7];
  const float* b3    = (const float*)d_in[8];

  char* ws   = (char*)d_ws;
  u16*  W1t  = (u16*)ws;                         // 256 KiB
  u16*  W2gt = (u16*)(ws + 512*256*2);           // 256 KiB
  float* Gv  = (float*)(ws + 512*256*2*2);       // 1 KiB
  float* BBv = (float*)(ws + 512*256*2*2 + 1024);// 1 KiB

  (void)hipFuncSetAttribute((const void*)edge_main,
                            hipFuncAttributeMaxDynamicSharedMemorySize, L_TOTAL);

  prep_wt<<<512, 256, 0, stream>>>(W1, W2, gamma, W1t, W2gt);
  prep_vec<<<256, 64, 0, stream>>>(W2, gamma, beta, b2, Gv, BBv);
  edge_main<<<8256, 512, L_TOTAL, stream>>>(emb, b1, b3, W3, Gv, BBv,
                                            W1t, W2gt, (float*)d_out);
}

// Round 8
// 551.991 us; speedup vs baseline: 2.6898x; 1.1214x over previous
//
#include <hip/hip_runtime.h>

typedef __attribute__((ext_vector_type(8))) short bf16x8;
typedef __attribute__((ext_vector_type(4))) float f32x4;
typedef unsigned short u16;
typedef unsigned int u32;

#define NN 1024
#define ETOT 523776
#define EPSV 1e-5f

// LDS layout (bytes)
#define L_PSUM 0      /* 64*17*4 = 4352 */
#define L_PSQ  4352   /* 4352 */
#define L_SSC  8704   /* 256 */
#define L_SSM  8960   /* 256 */
#define L_B1   9216   /* 2048 */
#define L_G    11264  /* 1024 */
#define L_BB   12288  /* 1024 */
#define L_W3   13312  /* 1024 */
#define L_TILE 14336  /* 64 KiB: A1 [64][256]bf16 (swz) aliased under h1 [64][512]bf16 (swz) */
#define L_TOTAL 79872 /* <= 81920: 2 blocks/CU */

__device__ __forceinline__ u16 f2bf(float f) {
  union { float f; u32 u; } v; v.f = f;
  u32 r = v.u + 0x7FFFu + ((v.u >> 16) & 1u);   // RNE, finite inputs only
  return (u16)(r >> 16);
}

// hardware packed f32x2 -> bf16x2 (RNE), low = a, high = b
__device__ __forceinline__ u32 cvtpk(float a, float b) {
  u32 r;
  asm("v_cvt_pk_bf16_f32 %0, %1, %2" : "=v"(r) : "v"(a), "v"(b));
  return r;
}

// row-dependent XOR mask: 8 distinct 16B slots + bit5 from row bit3
__device__ __forceinline__ int swz(int row) {
  return ((row & 7) << 4) ^ ((row & 8) << 2);
}

// ---- prep: W1^T [512][256] bf16 and (gamma-scaled) W2^T [256][512] bf16 ----
__global__ void prep_wt(const float* __restrict__ W1, const float* __restrict__ W2,
                        const float* __restrict__ gammav,
                        u16* __restrict__ W1t, u16* __restrict__ W2gt) {
  int idx = blockIdx.x * 256 + threadIdx.x;      // [0, 131072)
  { int n = idx >> 8, k = idx & 255; W1t[idx] = f2bf(W1[k*512 + n]); }
  { int o = idx >> 9, c = idx & 511; W2gt[idx] = f2bf(gammav[c] * W2[c*256 + o]); }
}

// ---- prep: G[o] = sum_c gamma[c]*W2[c,o]; BB[o] = b2[o] + sum_c beta[c]*W2[c,o] ----
__global__ void prep_vec(const float* __restrict__ W2, const float* __restrict__ gammav,
                         const float* __restrict__ betav, const float* __restrict__ b2v,
                         float* __restrict__ Gv, float* __restrict__ BBv) {
  int o = blockIdx.x, t = threadIdx.x;           // 256 blocks x 64 threads
  float g = 0.f, bb = 0.f;
  for (int c = t; c < 512; c += 64) {
    float w = W2[c*256 + o];
    g  += gammav[c] * w;
    bb += betav[c]  * w;
  }
  #pragma unroll
  for (int off = 1; off < 64; off <<= 1) {
    g  += __shfl_xor(g,  off, 64);
    bb += __shfl_xor(bb, off, 64);
  }
  if (t == 0) { Gv[o] = g; BBv[o] = bb + b2v[o]; }
}

// ---- main fused kernel: one block = 8x8 node tile = 64 edge rows (straight-line) ----
__launch_bounds__(512, 4)
__global__ void edge_main(const float* __restrict__ emb,
                          const float* __restrict__ b1v,
                          const float* __restrict__ b3v,
                          const float* __restrict__ w3v,
                          const float* __restrict__ Gv,
                          const float* __restrict__ BBv,
                          const u16* __restrict__ W1t,
                          const u16* __restrict__ W2gt,
                          float* __restrict__ out) {
  extern __shared__ char smem[];
  float* psum = (float*)(smem + L_PSUM);
  float* psq  = (float*)(smem + L_PSQ);
  float* ssc  = (float*)(smem + L_SSC);
  float* ssm  = (float*)(smem + L_SSM);
  float* sb1  = (float*)(smem + L_B1);
  float* sG   = (float*)(smem + L_G);
  float* sBB  = (float*)(smem + L_BB);
  float* sw3  = (float*)(smem + L_W3);
  char*  tile = smem + L_TILE;

  const int tid  = threadIdx.x;
  const int wave = tid >> 6;
  const int lane = tid & 63;
  const int llo  = lane & 15;
  const int lhi  = lane >> 4;
  const int sw   = swz(llo);
  const int trow = tid >> 3, cg = tid & 7;
  const int sa   = trow >> 3, sb = trow & 7;
  const int srs  = swz(trow);

  // exact upper-triangle (incl. diagonal) tile mapping: 8256 blocks
  int kblk = blockIdx.x;
  int bi = (int)((257.0f - sqrtf(66049.0f - 8.0f*(float)kblk)) * 0.5f);
  bi = bi < 0 ? 0 : (bi > 127 ? 127 : bi);
  while (bi*128 - bi*(bi-1)/2 > kblk) --bi;
  while ((bi+1)*128 - (bi+1)*bi/2 <= kblk) ++bi;
  const int bj = bi + (kblk - (bi*128 - bi*(bi-1)/2));
  const int i0 = bi*8, j0 = bj*8;

  // ---- stage A1 = [e_i - e_j | e_i * e_j] bf16, XOR-swizzled [64][256] (512B rows) ----
  {
    const float4* pei = (const float4*)(emb + (i0 + sa)*128 + cg*16);
    const float4* pej = (const float4*)(emb + (j0 + sb)*128 + cg*16);
    float4 eA0 = pei[0], eA1 = pei[1], eA2 = pei[2], eA3 = pei[3];
    float4 eB0 = pej[0], eB1 = pej[1], eB2 = pej[2], eB3 = pej[3];
    char* rowp = tile + trow*512;
    uint4 v;
    v.x = cvtpk(eA0.x-eB0.x, eA0.y-eB0.y); v.y = cvtpk(eA0.z-eB0.z, eA0.w-eB0.w);
    v.z = cvtpk(eA1.x-eB1.x, eA1.y-eB1.y); v.w = cvtpk(eA1.z-eB1.z, eA1.w-eB1.w);
    *(uint4*)(rowp + ((cg*32) ^ srs)) = v;
    v.x = cvtpk(eA2.x-eB2.x, eA2.y-eB2.y); v.y = cvtpk(eA2.z-eB2.z, eA2.w-eB2.w);
    v.z = cvtpk(eA3.x-eB3.x, eA3.y-eB3.y); v.w = cvtpk(eA3.z-eB3.z, eA3.w-eB3.w);
    *(uint4*)(rowp + ((cg*32 + 16) ^ srs)) = v;
    v.x = cvtpk(eA0.x*eB0.x, eA0.y*eB0.y); v.y = cvtpk(eA0.z*eB0.z, eA0.w*eB0.w);
    v.z = cvtpk(eA1.x*eB1.x, eA1.y*eB1.y); v.w = cvtpk(eA1.z*eB1.z, eA1.w*eB1.w);
    *(uint4*)(rowp + ((256 + cg*32) ^ srs)) = v;
    v.x = cvtpk(eA2.x*eB2.x, eA2.y*eB2.y); v.y = cvtpk(eA2.z*eB2.z, eA2.w*eB2.w);
    v.z = cvtpk(eA3.x*eB3.x, eA3.y*eB3.y); v.w = cvtpk(eA3.z*eB3.z, eA3.w*eB3.w);
    *(uint4*)(rowp + ((256 + cg*32 + 16) ^ srs)) = v;
  }
  sb1[tid] = b1v[tid];
  if (tid < 256) { sG[tid] = Gv[tid]; sBB[tid] = BBv[tid]; sw3[tid] = w3v[tid]; }
  __syncthreads();                               // B0: stage + consts visible

  // ---- GEMM1: A1[64x256] @ W1[256x512]; wave owns 64-col stripe ----
  f32x4 acc1[4][4];
  #pragma unroll
  for (int m = 0; m < 4; ++m)
    #pragma unroll
    for (int n = 0; n < 4; ++n)
      acc1[m][n] = (f32x4){0.f, 0.f, 0.f, 0.f};

  const u16* w1p = W1t + (wave*64 + llo)*256 + lhi*8;
  #pragma unroll
  for (int kb = 0; kb < 8; ++kb) {
    bf16x8 af[4], bfr[4];
    #pragma unroll
    for (int m = 0; m < 4; ++m)
      af[m] = *(const bf16x8*)(tile + (m*16 + llo)*512 + ((kb*64 + lhi*16) ^ sw));
    #pragma unroll
    for (int n = 0; n < 4; ++n)
      bfr[n] = *(const bf16x8*)(w1p + n*4096 + kb*32);
    #pragma unroll
    for (int m = 0; m < 4; ++m)
      #pragma unroll
      for (int n = 0; n < 4; ++n)
        acc1[m][n] = __builtin_amdgcn_mfma_f32_16x16x32_bf16(af[m], bfr[n], acc1[m][n], 0, 0, 0);
  }
  __syncthreads();                               // B1: all GEMM1 A1-reads done

  // ---- fused: +b1, relu, write h1 (bf16 via cvt_pk, swz) + LN partials (3-step shfl) ----
  {
    float bb[4];
    #pragma unroll
    for (int n = 0; n < 4; ++n) bb[n] = sb1[wave*64 + n*16 + llo];
    const int c0 = 2*(wave*64 + llo);
    #pragma unroll
    for (int m = 0; m < 4; ++m) {
      #pragma unroll
      for (int q = 0; q < 4; ++q) {
        int r = m*16 + lhi*4 + q;
        int rs2 = swz(r);
        char* rowp = tile + r*1024;
        float v0 = fmaxf(acc1[m][0][q] + bb[0], 0.f);
        float v1 = fmaxf(acc1[m][1][q] + bb[1], 0.f);
        float v2 = fmaxf(acc1[m][2][q] + bb[2], 0.f);
        float v3 = fmaxf(acc1[m][3][q] + bb[3], 0.f);
        u32 w01 = cvtpk(v0, v1);
        u32 w23 = cvtpk(v2, v3);
        *(u16*)(rowp + ((c0      ) ^ rs2)) = (u16)w01;
        *(u16*)(rowp + ((c0 + 32 ) ^ rs2)) = (u16)(w01 >> 16);
        *(u16*)(rowp + ((c0 + 64 ) ^ rs2)) = (u16)w23;
        *(u16*)(rowp + ((c0 + 96 ) ^ rs2)) = (u16)(w23 >> 16);
        float sum = (v0 + v1) + (v2 + v3);
        float sq  = fmaf(v3, v3, fmaf(v2, v2, fmaf(v1, v1, v0*v0)));
        sum += __shfl_xor(sum, 1, 64);
        sq  += __shfl_xor(sq,  1, 64);
        sum += __shfl_xor(sum, 2, 64);
        sq  += __shfl_xor(sq,  2, 64);
        sum += __shfl_xor(sum, 4, 64);
        sq  += __shfl_xor(sq,  4, 64);
        if ((lane & 7) == 0) {
          int c = wave*2 + ((lane >> 3) & 1);
          psum[r*17 + c] = sum;
          psq [r*17 + c] = sq;
        }
      }
    }
  }
  __syncthreads();                               // B2: h1 + partials visible

  // ---- stats (wave0) overlapped with GEMM2 (all waves) ----
  if (tid < 64) {
    float s = 0.f, ss = 0.f;
    #pragma unroll
    for (int k = 0; k < 16; ++k) { s += psum[tid*17 + k]; ss += psq[tid*17 + k]; }
    float mu  = s * (1.f/512.f);
    float var = ss * (1.f/512.f) - mu*mu;
    float sc  = rsqrtf(var + EPSV);
    ssc[tid] = sc;
    ssm[tid] = mu * sc;
  }

  // GEMM2: h1[64x512] @ W2g[512x256]; wave owns 32-col stripe
  f32x4 acc2[4][2];
  #pragma unroll
  for (int m = 0; m < 4; ++m) { acc2[m][0] = (f32x4){0,0,0,0}; acc2[m][1] = (f32x4){0,0,0,0}; }

  const u16* w2p = W2gt + (wave*32 + llo)*512 + lhi*8;
  #pragma unroll 4
  for (int kb = 0; kb < 16; ++kb) {
    bf16x8 af[4], bfr[2];
    #pragma unroll
    for (int m = 0; m < 4; ++m)
      af[m] = *(const bf16x8*)(tile + (m*16 + llo)*1024 + ((kb*64 + lhi*16) ^ sw));
    #pragma unroll
    for (int n = 0; n < 2; ++n)
      bfr[n] = *(const bf16x8*)(w2p + n*8192 + kb*32);
    #pragma unroll
    for (int m = 0; m < 4; ++m)
      #pragma unroll
      for (int n = 0; n < 2; ++n)
        acc2[m][n] = __builtin_amdgcn_mfma_f32_16x16x32_bf16(af[m], bfr[n], acc2[m][n], 0, 0, 0);
  }
  __syncthreads();                               // B3: stats visible (GEMM2 done)

  // ---- epilogue2: LN-affine + relu + W3 dot, per-row reduce (3-step shfl) ----
  #pragma unroll
  for (int m = 0; m < 4; ++m) {
    float cgv[2], cbv[2], cwv[2];
    #pragma unroll
    for (int n = 0; n < 2; ++n) {
      int col = wave*32 + n*16 + llo;
      cgv[n] = sG[col]; cbv[n] = sBB[col]; cwv[n] = sw3[col];
    }
    #pragma unroll
    for (int q = 0; q < 4; ++q) {
      int r = m*16 + lhi*4 + q;
      float sc = ssc[r], sm = ssm[r];
      float s = 0.f;
      #pragma unroll
      for (int n = 0; n < 2; ++n) {
        float v = sc*acc2[m][n][q] - sm*cgv[n] + cbv[n];
        v = fmaxf(v, 0.f);
        s += v * cwv[n];
      }
      s += __shfl_xor(s, 1, 64);
      s += __shfl_xor(s, 2, 64);
      s += __shfl_xor(s, 4, 64);
      if ((lane & 7) == 0) psum[r*17 + wave*2 + ((lane >> 3) & 1)] = s;
    }
  }
  __syncthreads();                               // B4: psum ready

  // ---- flush logits + pairs ----
  if (tid < 64) {
    float s = 0.f;
    #pragma unroll
    for (int k = 0; k < 16; ++k) s += psum[tid*17 + k];
    float logit = s + b3v[0];
    int a = tid >> 3, b = tid & 7;
    int i = i0 + a, j = j0 + b;
    if (i < j) {
      int e = i*(2*NN - i - 1)/2 + (j - i - 1);
      out[e] = logit;
      out[ETOT + 2*e]     = (float)i;
      out[ETOT + 2*e + 1] = (float)j;
    }
  }
}

extern "C" void kernel_launch(void* const* d_in, const int* in_sizes, int n_in,
                              void* d_out, int out_size, void* d_ws, size_t ws_size,
                              hipStream_t stream) {
  const float* emb   = (const float*)d_in[0];
  const float* W1    = (const float*)d_in[1];
  const float* b1    = (const float*)d_in[2];
  const float* gamma = (const float*)d_in[3];
  const float* beta  = (const float*)d_in[4];
  const float* W2    = (const float*)d_in[5];
  const float* b2    = (const float*)d_in[6];
  const float* W3    = (const float*)d_in[7];
  const float* b3    = (const float*)d_in[8];

  char* ws   = (char*)d_ws;
  u16*  W1t  = (u16*)ws;                         // 256 KiB
  u16*  W2gt = (u16*)(ws + 512*256*2);           // 256 KiB
  float* Gv  = (float*)(ws + 512*256*2*2);       // 1 KiB
  float* BBv = (float*)(ws + 512*256*2*2 + 1024);// 1 KiB

  (void)hipFuncSetAttribute((const void*)edge_main,
                            hipFuncAttributeMaxDynamicSharedMemorySize, L_TOTAL);

  prep_wt<<<512, 256, 0, stream>>>(W1, W2, gamma, W1t, W2gt);
  prep_vec<<<256, 64, 0, stream>>>(W2, gamma, beta, b2, Gv, BBv);
  edge_main<<<8256, 512, L_TOTAL, stream>>>(emb, b1, b3, W3, Gv, BBv,
                                            W1t, W2gt, (float*)d_out);
}

// Round 9
// 511.563 us; speedup vs baseline: 2.9024x; 1.0790x over previous
//
#include <hip/hip_runtime.h>

typedef __attribute__((ext_vector_type(8))) short bf16x8;
typedef __attribute__((ext_vector_type(16))) float f32x16;
typedef unsigned short u16;
typedef unsigned int u32;

#define NN 1024
#define ETOT 523776
#define EPSV 1e-5f

// LDS layout (bytes)
#define L_PSUM 0      /* 64*17*4 = 4352 */
#define L_PSQ  4352   /* 4352 */
#define L_SSC  8704   /* 256 */
#define L_SSM  8960   /* 256 */
#define L_B1   9216   /* 2048 */
#define L_G    11264  /* 1024 */
#define L_BB   12288  /* 1024 */
#define L_W3   13312  /* 1024 */
#define L_TILE 14336  /* 64 KiB: A1 [64][256]bf16 (swz, 32K) aliased under h1 [64][512]bf16 (swz, 64K) */
#define L_TOTAL 79872 /* <= 81920: 2 blocks/CU */

__device__ __forceinline__ u16 f2bf(float f) {
  union { float f; u32 u; } v; v.f = f;
  u32 r = v.u + 0x7FFFu + ((v.u >> 16) & 1u);   // RNE, finite inputs only
  return (u16)(r >> 16);
}

// hardware packed f32x2 -> bf16x2 (RNE), low = a, high = b
__device__ __forceinline__ u32 cvtpk(float a, float b) {
  u32 r;
  asm("v_cvt_pk_bf16_f32 %0, %1, %2" : "=v"(r) : "v"(a), "v"(b));
  return r;
}

// ---- prep: W1^T [512][256] bf16 and (gamma-scaled) W2^T [256][512] bf16 ----
__global__ void prep_wt(const float* __restrict__ W1, const float* __restrict__ W2,
                        const float* __restrict__ gammav,
                        u16* __restrict__ W1t, u16* __restrict__ W2gt) {
  int idx = blockIdx.x * 256 + threadIdx.x;      // [0, 131072)
  { int n = idx >> 8, k = idx & 255; W1t[idx] = f2bf(W1[k*512 + n]); }
  { int o = idx >> 9, c = idx & 511; W2gt[idx] = f2bf(gammav[c] * W2[c*256 + o]); }
}

// ---- prep: G[o] = sum_c gamma[c]*W2[c,o]; BB[o] = b2[o] + sum_c beta[c]*W2[c,o] ----
__global__ void prep_vec(const float* __restrict__ W2, const float* __restrict__ gammav,
                         const float* __restrict__ betav, const float* __restrict__ b2v,
                         float* __restrict__ Gv, float* __restrict__ BBv) {
  int o = blockIdx.x, t = threadIdx.x;           // 256 blocks x 64 threads
  float g = 0.f, bb = 0.f;
  for (int c = t; c < 512; c += 64) {
    float w = W2[c*256 + o];
    g  += gammav[c] * w;
    bb += betav[c]  * w;
  }
  #pragma unroll
  for (int off = 1; off < 64; off <<= 1) {
    g  += __shfl_xor(g,  off, 64);
    bb += __shfl_xor(bb, off, 64);
  }
  if (t == 0) { Gv[o] = g; BBv[o] = bb + b2v[o]; }
}

// ---- main fused kernel: one block = 8x8 node tile = 64 edge rows ----
// Both GEMMs operand-swapped (32x32x16): C col = lane&31 = EDGE -> LN stats
// and epilogue reductions are in-lane; no shfl chains.
__launch_bounds__(512, 4)
__global__ void edge_main(const float* __restrict__ emb,
                          const float* __restrict__ b1v,
                          const float* __restrict__ b3v,
                          const float* __restrict__ w3v,
                          const float* __restrict__ Gv,
                          const float* __restrict__ BBv,
                          const u16* __restrict__ W1t,
                          const u16* __restrict__ W2gt,
                          float* __restrict__ out) {
  extern __shared__ char smem[];
  float* psum = (float*)(smem + L_PSUM);         // [64][17]
  float* psq  = (float*)(smem + L_PSQ);          // [64][17]
  float* ssc  = (float*)(smem + L_SSC);
  float* ssm  = (float*)(smem + L_SSM);
  float* sb1  = (float*)(smem + L_B1);
  float* sG   = (float*)(smem + L_G);
  float* sBB  = (float*)(smem + L_BB);
  float* sw3  = (float*)(smem + L_W3);
  char*  tile = smem + L_TILE;

  const int tid  = threadIdx.x;
  const int wave = tid >> 6;
  const int lane = tid & 63;
  const int l31  = lane & 31;
  const int hi   = lane >> 5;
  const int lsw  = l31 << 4;                     // row-swizzle for tile reads (32 slots)

  // exact upper-triangle (incl. diagonal) tile mapping: 8256 blocks
  int kblk = blockIdx.x;
  int bi = (int)((257.0f - sqrtf(66049.0f - 8.0f*(float)kblk)) * 0.5f);
  bi = bi < 0 ? 0 : (bi > 127 ? 127 : bi);
  while (bi*128 - bi*(bi-1)/2 > kblk) --bi;
  while ((bi+1)*128 - (bi+1)*bi/2 <= kblk) ++bi;
  const int bj = bi + (kblk - (bi*128 - bi*(bi-1)/2));
  const int i0 = bi*8, j0 = bj*8;

  // ---- stage A1 = [e_i - e_j | e_i * e_j] bf16, [64][256], swz = (row&31)<<4 ----
  {
    const int trow = tid >> 3, cg = tid & 7;
    const int sa = trow >> 3, sb = trow & 7;
    const int srs = (trow & 31) << 4;
    const float4* pei = (const float4*)(emb + (i0 + sa)*128 + cg*16);
    const float4* pej = (const float4*)(emb + (j0 + sb)*128 + cg*16);
    float4 eA0 = pei[0], eA1 = pei[1], eA2 = pei[2], eA3 = pei[3];
    float4 eB0 = pej[0], eB1 = pej[1], eB2 = pej[2], eB3 = pej[3];
    char* rowp = tile + trow*512;
    uint4 v;
    v.x = cvtpk(eA0.x-eB0.x, eA0.y-eB0.y); v.y = cvtpk(eA0.z-eB0.z, eA0.w-eB0.w);
    v.z = cvtpk(eA1.x-eB1.x, eA1.y-eB1.y); v.w = cvtpk(eA1.z-eB1.z, eA1.w-eB1.w);
    *(uint4*)(rowp + ((cg*32) ^ srs)) = v;
    v.x = cvtpk(eA2.x-eB2.x, eA2.y-eB2.y); v.y = cvtpk(eA2.z-eB2.z, eA2.w-eB2.w);
    v.z = cvtpk(eA3.x-eB3.x, eA3.y-eB3.y); v.w = cvtpk(eA3.z-eB3.z, eA3.w-eB3.w);
    *(uint4*)(rowp + ((cg*32 + 16) ^ srs)) = v;
    v.x = cvtpk(eA0.x*eB0.x, eA0.y*eB0.y); v.y = cvtpk(eA0.z*eB0.z, eA0.w*eB0.w);
    v.z = cvtpk(eA1.x*eB1.x, eA1.y*eB1.y); v.w = cvtpk(eA1.z*eB1.z, eA1.w*eB1.w);
    *(uint4*)(rowp + ((256 + cg*32) ^ srs)) = v;
    v.x = cvtpk(eA2.x*eB2.x, eA2.y*eB2.y); v.y = cvtpk(eA2.z*eB2.z, eA2.w*eB2.w);
    v.z = cvtpk(eA3.x*eB3.x, eA3.y*eB3.y); v.w = cvtpk(eA3.z*eB3.z, eA3.w*eB3.w);
    *(uint4*)(rowp + ((256 + cg*32 + 16) ^ srs)) = v;
  }
  sb1[tid] = b1v[tid];
  if (tid < 256) { sG[tid] = Gv[tid]; sBB[tid] = BBv[tid]; sw3[tid] = w3v[tid]; }
  __syncthreads();                               // B0

  f32x16 zero16;
  #pragma unroll
  for (int i = 0; i < 16; ++i) zero16[i] = 0.f;

  // ---- GEMM1 (swapped): h1^T[c][e] = W1^T[c][k] x A1^T[k][e]; wave owns 64 c ----
  f32x16 acc00 = zero16, acc01 = zero16, acc10 = zero16, acc11 = zero16;
  {
    const u16* w1p = W1t + (wave*64 + l31)*256 + hi*8;   // A-frag: row c, k = hi*8+j
    char* b0p = tile + l31*512;                          // B-frag: col e=l31
    char* b1p = tile + (l31 + 32)*512;                   // col e=l31+32
    #pragma unroll
    for (int kk = 0; kk < 16; ++kk) {
      bf16x8 a0 = *(const bf16x8*)(w1p + kk*16);
      bf16x8 a1 = *(const bf16x8*)(w1p + 8192 + kk*16);  // +32 c-rows
      const int rb = kk*32 + hi*16;
      bf16x8 b0 = *(const bf16x8*)(b0p + (rb ^ lsw));
      bf16x8 b1 = *(const bf16x8*)(b1p + (rb ^ lsw));
      acc00 = __builtin_amdgcn_mfma_f32_32x32x16_bf16(a0, b0, acc00, 0, 0, 0);
      acc01 = __builtin_amdgcn_mfma_f32_32x32x16_bf16(a0, b1, acc01, 0, 0, 0);
      acc10 = __builtin_amdgcn_mfma_f32_32x32x16_bf16(a1, b0, acc10, 0, 0, 0);
      acc11 = __builtin_amdgcn_mfma_f32_32x32x16_bf16(a1, b1, acc11, 0, 0, 0);
    }
  }
  __syncthreads();                               // B1: A1 reads done (h1 may overwrite)

  // ---- +b1, relu, cvt_pk -> h1[e][c] bf16 (8B runs, conflict-free), in-lane LN stats ----
  {
    float sum0 = 0.f, sq0 = 0.f, sum1 = 0.f, sq1 = 0.f;
    char* h1r0 = tile + l31*1024;
    char* h1r1 = tile + (l31 + 32)*1024;
    auto h1pass = [&](const f32x16& A0, const f32x16& A1v, int mbase) {
      #pragma unroll
      for (int rg = 0; rg < 16; rg += 4) {
        const int cbase = mbase + (rg >> 2)*8 + hi*4;    // 4 consecutive c
        const float ba = sb1[cbase+0], bbv = sb1[cbase+1],
                    bc = sb1[cbase+2], bd = sb1[cbase+3];
        float v0 = fmaxf(A0[rg+0] + ba, 0.f);
        float v1 = fmaxf(A0[rg+1] + bbv, 0.f);
        float v2 = fmaxf(A0[rg+2] + bc, 0.f);
        float v3 = fmaxf(A0[rg+3] + bd, 0.f);
        uint2 p; p.x = cvtpk(v0, v1); p.y = cvtpk(v2, v3);
        *(uint2*)(h1r0 + ((2*cbase) ^ lsw)) = p;
        sum0 += (v0 + v1) + (v2 + v3);
        sq0 = fmaf(v0,v0, sq0); sq0 = fmaf(v1,v1, sq0);
        sq0 = fmaf(v2,v2, sq0); sq0 = fmaf(v3,v3, sq0);
        float w0 = fmaxf(A1v[rg+0] + ba, 0.f);
        float w1 = fmaxf(A1v[rg+1] + bbv, 0.f);
        float w2 = fmaxf(A1v[rg+2] + bc, 0.f);
        float w3_ = fmaxf(A1v[rg+3] + bd, 0.f);
        uint2 q; q.x = cvtpk(w0, w1); q.y = cvtpk(w2, w3_);
        *(uint2*)(h1r1 + ((2*cbase) ^ lsw)) = q;
        sum1 += (w0 + w1) + (w2 + w3_);
        sq1 = fmaf(w0,w0, sq1); sq1 = fmaf(w1,w1, sq1);
        sq1 = fmaf(w2,w2, sq1); sq1 = fmaf(w3_,w3_, sq1);
      }
    };
    h1pass(acc00, acc01, wave*64);
    h1pass(acc10, acc11, wave*64 + 32);
    const int pc = wave*2 + hi;
    psum[l31*17 + pc]        = sum0;
    psq [l31*17 + pc]        = sq0;
    psum[(l31 + 32)*17 + pc] = sum1;
    psq [(l31 + 32)*17 + pc] = sq1;
  }
  __syncthreads();                               // B2: h1 + partials visible

  // ---- stats (wave0) overlapped with GEMM2 (all waves) ----
  if (tid < 64) {
    float s = 0.f, ss = 0.f;
    #pragma unroll
    for (int k = 0; k < 16; ++k) { s += psum[tid*17 + k]; ss += psq[tid*17 + k]; }
    float mu  = s * (1.f/512.f);
    float var = ss * (1.f/512.f) - mu*mu;
    float sc  = rsqrtf(var + EPSV);
    ssc[tid] = sc;
    ssm[tid] = mu * sc;
  }

  // ---- GEMM2 (swapped): out2^T[o][e] = W2g^T[o][c] x h1^T[c][e]; wave owns 32 o ----
  f32x16 acc20 = zero16, acc21 = zero16;
  {
    const u16* w2p = W2gt + (wave*32 + l31)*512 + hi*8;
    char* h1r0 = tile + l31*1024;
    char* h1r1 = tile + (l31 + 32)*1024;
    #pragma unroll 8
    for (int kk = 0; kk < 32; ++kk) {
      bf16x8 a = *(const bf16x8*)(w2p + kk*16);
      const int rb = kk*32 + hi*16;
      bf16x8 b0 = *(const bf16x8*)(h1r0 + (rb ^ lsw));
      bf16x8 b1 = *(const bf16x8*)(h1r1 + (rb ^ lsw));
      acc20 = __builtin_amdgcn_mfma_f32_32x32x16_bf16(a, b0, acc20, 0, 0, 0);
      acc21 = __builtin_amdgcn_mfma_f32_32x32x16_bf16(a, b1, acc21, 0, 0, 0);
    }
  }
  __syncthreads();                               // B3: stats visible

  // ---- epilogue2: LN-affine + relu + W3 dot, fully in-lane ----
  {
    const float scA = ssc[l31],      smA = ssm[l31];
    const float scB = ssc[l31 + 32], smB = ssm[l31 + 32];
    float part0 = 0.f, part1 = 0.f;
    #pragma unroll
    for (int rg = 0; rg < 16; ++rg) {
      const int o = wave*32 + (rg & 3) + 8*(rg >> 2) + 4*hi;
      const float g = sG[o], bb = sBB[o], w3 = sw3[o];
      float t0 = fmaxf(fmaf(scA, acc20[rg], fmaf(-smA, g, bb)), 0.f);
      part0 = fmaf(t0, w3, part0);
      float t1 = fmaxf(fmaf(scB, acc21[rg], fmaf(-smB, g, bb)), 0.f);
      part1 = fmaf(t1, w3, part1);
    }
    const int pc = wave*2 + hi;
    psum[l31*17 + pc]        = part0;
    psum[(l31 + 32)*17 + pc] = part1;
  }
  __syncthreads();                               // B4: psum ready

  // ---- flush logits + pairs ----
  if (tid < 64) {
    float s = 0.f;
    #pragma unroll
    for (int k = 0; k < 16; ++k) s += psum[tid*17 + k];
    float logit = s + b3v[0];
    int a = tid >> 3, b = tid & 7;
    int i = i0 + a, j = j0 + b;
    if (i < j) {
      int e = i*(2*NN - i - 1)/2 + (j - i - 1);
      out[e] = logit;
      out[ETOT + 2*e]     = (float)i;
      out[ETOT + 2*e + 1] = (float)j;
    }
  }
}

extern "C" void kernel_launch(void* const* d_in, const int* in_sizes, int n_in,
                              void* d_out, int out_size, void* d_ws, size_t ws_size,
                              hipStream_t stream) {
  const float* emb   = (const float*)d_in[0];
  const float* W1    = (const float*)d_in[1];
  const float* b1    = (const float*)d_in[2];
  const float* gamma = (const float*)d_in[3];
  const float* beta  = (const float*)d_in[4];
  const float* W2    = (const float*)d_in[5];
  const float* b2    = (const float*)d_in[6];
  const float* W3    = (const float*)d_in[7];
  const float* b3    = (const float*)d_in[8];

  char* ws   = (char*)d_ws;
  u16*  W1t  = (u16*)ws;                         // 256 KiB
  u16*  W2gt = (u16*)(ws + 512*256*2);           // 256 KiB
  float* Gv  = (float*)(ws + 512*256*2*2);       // 1 KiB
  float* BBv = (float*)(ws + 512*256*2*2 + 1024);// 1 KiB

  (void)hipFuncSetAttribute((const void*)edge_main,
                            hipFuncAttributeMaxDynamicSharedMemorySize, L_TOTAL);

  prep_wt<<<512, 256, 0, stream>>>(W1, W2, gamma, W1t, W2gt);
  prep_vec<<<256, 64, 0, stream>>>(W2, gamma, beta, b2, Gv, BBv);
  edge_main<<<8256, 512, L_TOTAL, stream>>>(emb, b1, b3, W3, Gv, BBv,
                                            W1t, W2gt, (float*)d_out);
}